// Round 1
// baseline (205.493 us; speedup 1.0000x reference)
//
#include <hip/hip_runtime.h>
#include <math.h>

#define B_IMG 16
#define P_N   2048

constexpr float SCORE_T = 0.05f;
constexpr float NMS_T   = 0.5f;
constexpr float XCLIP   = 4.135166556742356f; // log(1000/16)
constexpr float IMW     = 1333.0f;
constexpr float IMH     = 800.0f;

// monotone float->uint mapping (ascending float order, incl +inf)
__device__ __forceinline__ unsigned int fkey(float f) {
    unsigned int u = __float_as_uint(f);
    return (u & 0x80000000u) ? ~u : (u | 0x80000000u);
}

// ---------------------------------------------------------------------------
// Kernel A: score + decode + clip + stable sort; writes sorted rows to out
// ---------------------------------------------------------------------------
__global__ __launch_bounds__(1024) void prep_sort_kernel(
    const float* __restrict__ cls, const float* __restrict__ codes,
    const float* __restrict__ props, float* __restrict__ out,
    float4* __restrict__ packed, int write_packed)
{
#pragma clang fp contract(off)
    __shared__ float4 sbox[P_N];
    __shared__ float  ssc[P_N];
    __shared__ unsigned long long skey[P_N];

    const int img = blockIdx.x;
    const int tid = threadIdx.x;

    for (int p = tid; p < P_N; p += 1024) {
        float2 lg = reinterpret_cast<const float2*>(cls)[img * P_N + p];
        float score = 1.0f / (1.0f + expf(lg.x - lg.y));

        float4 pb = reinterpret_cast<const float4*>(props)[img * P_N + p];
        float4 c  = reinterpret_cast<const float4*>(codes)[(img * P_N + p) * 2 + 1];

        float w  = pb.z - pb.x + 1.0f;
        float h  = pb.w - pb.y + 1.0f;
        float cx = pb.x + 0.5f * w;
        float cy = pb.y + 0.5f * h;

        float dx = c.x / 10.0f;
        float dy = c.y / 10.0f;
        float dw = fminf(c.z / 5.0f, XCLIP);
        float dh = fminf(c.w / 5.0f, XCLIP);

        float pcx = dx * w + cx;
        float pcy = dy * h + cy;
        float pw  = expf(dw) * w;
        float ph  = expf(dh) * h;

        float x1 = pcx - 0.5f * pw;
        float y1 = pcy - 0.5f * ph;
        float x2 = (pcx + 0.5f * pw) - 1.0f;
        float y2 = (pcy + 0.5f * ph) - 1.0f;

        x1 = fminf(fmaxf(x1, 0.0f), IMW - 1.0f);
        y1 = fminf(fmaxf(y1, 0.0f), IMH - 1.0f);
        x2 = fminf(fmaxf(x2, 0.0f), IMW - 1.0f);
        y2 = fminf(fmaxf(y2, 0.0f), IMH - 1.0f);

        sbox[p] = make_float4(x1, y1, x2, y2);
        ssc[p]  = score;

        float key = (score > SCORE_T) ? -score : __int_as_float(0x7f800000); // +inf
        skey[p] = (((unsigned long long)fkey(key)) << 32) | (unsigned int)p;
    }
    __syncthreads();

    // bitonic sort ascending over 2048 u64 keys (stable argsort replica)
    for (int k = 2; k <= P_N; k <<= 1) {
        for (int j = k >> 1; j > 0; j >>= 1) {
            for (int t = tid; t < P_N; t += 1024) {
                int ixj = t ^ j;
                if (ixj > t) {
                    unsigned long long a = skey[t], b = skey[ixj];
                    bool up = ((t & k) == 0);
                    if ((a > b) == up) { skey[t] = b; skey[ixj] = a; }
                }
            }
            __syncthreads();
        }
    }

    // gather + write sorted rows
    for (int e = tid; e < P_N; e += 1024) {
        unsigned long long kv = skey[e];
        int idx = (int)(kv & 0xFFFFFFFFull);
        float4 b4 = sbox[idx];
        float  s  = ssc[idx];
        float* o = out + ((size_t)img * P_N + e) * 5;
        o[0] = b4.x; o[1] = b4.y; o[2] = b4.z; o[3] = b4.w; o[4] = s;
        if (write_packed) packed[img * P_N + e] = b4;
    }
}

// ---------------------------------------------------------------------------
// Kernel B: suppression bitmask rows (j > i && IoU > 0.5), ballot-packed
// ---------------------------------------------------------------------------
#define ROWS_PB 8
__global__ __launch_bounds__(512) void mask_kernel(
    const float4* __restrict__ packed, unsigned int* __restrict__ mask)
{
#pragma clang fp contract(off)
    __shared__ float4 sb[P_N];
    const int blocks_per_img = P_N / ROWS_PB; // 256
    const int img = blockIdx.x / blocks_per_img;
    const int rb  = blockIdx.x % blocks_per_img;
    const int tid = threadIdx.x;

    for (int j = tid; j < P_N; j += 512) sb[j] = packed[img * P_N + j];
    __syncthreads();

    const int wave = tid >> 6;
    const int lane = tid & 63;
    const int i = rb * ROWS_PB + wave;

    float4 bi = sb[i];
    float area_i = (bi.z - bi.x) * (bi.w - bi.y);

    unsigned int myword = 0;
    for (int c = 0; c < 32; ++c) {
        int j = c * 64 + lane;
        bool sup = false;
        if (j > i) {
            float4 bj = sb[j];
            float area_j = (bj.z - bj.x) * (bj.w - bj.y);
            float ltx = fmaxf(bi.x, bj.x);
            float lty = fmaxf(bi.y, bj.y);
            float rbx = fminf(bi.z, bj.z);
            float rby = fminf(bi.w, bj.w);
            float wx = fmaxf(rbx - ltx, 0.0f);
            float wy = fmaxf(rby - lty, 0.0f);
            float inter = wx * wy;
            float denom = ((area_i + area_j) - inter) + 1e-9f;
            sup = (inter / denom) > NMS_T;
        }
        unsigned long long m = __ballot(sup);
        if ((lane >> 1) == c)
            myword = (lane & 1) ? (unsigned int)(m >> 32) : (unsigned int)m;
    }
    mask[((size_t)img * P_N + i) * 64 + lane] = myword;
}

// ---------------------------------------------------------------------------
// Kernel C: sequential greedy cascade (1 wave per image), zero non-kept rows
// ---------------------------------------------------------------------------
template <bool USE_MASK>
__global__ __launch_bounds__(64) void nms_kernel(
    float* __restrict__ out, const unsigned int* __restrict__ mask)
{
#pragma clang fp contract(off)
    __shared__ float4 sb[P_N];
    const int img  = blockIdx.x;
    const int lane = threadIdx.x;

    unsigned int keep = 0;
    for (int b = 0; b < 32; ++b) {
        int p = lane * 32 + b;
        const float* o = out + ((size_t)img * P_N + p) * 5;
        if constexpr (!USE_MASK) sb[p] = make_float4(o[0], o[1], o[2], o[3]);
        if (o[4] > SCORE_T) keep |= (1u << b);
    }
    if constexpr (!USE_MASK) __syncthreads();

    if constexpr (USE_MASK) {
        const unsigned int* mrow = mask + (size_t)img * P_N * 64 + lane;
        constexpr int PF = 16;
        static_assert(P_N % PF == 0, "");
        unsigned int buf[PF];
#pragma unroll
        for (int k = 0; k < PF; ++k) buf[k] = mrow[(size_t)k * 64];
        for (int base = 0; base < P_N; base += PF) {
#pragma unroll
            for (int k = 0; k < PF; ++k) {
                int i = base + k;
                unsigned int m = buf[k];
                int nxt = i + PF;
                buf[k] = (nxt < P_N) ? mrow[(size_t)nxt * 64] : 0u;
                unsigned int kw =
                    (unsigned int)__builtin_amdgcn_readlane((int)keep, i >> 5);
                if ((kw >> (i & 31)) & 1u) keep &= ~m;
            }
        }
    } else {
        for (int i = 0; i < P_N; ++i) {
            unsigned int kw =
                (unsigned int)__builtin_amdgcn_readlane((int)keep, i >> 5);
            if ((kw >> (i & 31)) & 1u) {
                float4 bi = sb[i];
                float area_i = (bi.z - bi.x) * (bi.w - bi.y);
                unsigned int m = 0;
                for (int b = 0; b < 32; ++b) {
                    int j = lane * 32 + b;
                    if (j > i) {
                        float4 bj = sb[j];
                        float area_j = (bj.z - bj.x) * (bj.w - bj.y);
                        float ltx = fmaxf(bi.x, bj.x);
                        float lty = fmaxf(bi.y, bj.y);
                        float rbx = fminf(bi.z, bj.z);
                        float rby = fminf(bi.w, bj.w);
                        float wx = fmaxf(rbx - ltx, 0.0f);
                        float wy = fmaxf(rby - lty, 0.0f);
                        float inter = wx * wy;
                        float denom = ((area_i + area_j) - inter) + 1e-9f;
                        if ((inter / denom) > NMS_T) m |= (1u << b);
                    }
                }
                keep &= ~m;
            }
        }
    }

    // zero out non-kept rows
    for (int b = 0; b < 32; ++b) {
        if (!((keep >> b) & 1u)) {
            int p = lane * 32 + b;
            float* o = out + ((size_t)img * P_N + p) * 5;
            o[0] = 0.0f; o[1] = 0.0f; o[2] = 0.0f; o[3] = 0.0f; o[4] = 0.0f;
        }
    }
}

// ---------------------------------------------------------------------------
extern "C" void kernel_launch(void* const* d_in, const int* in_sizes, int n_in,
                              void* d_out, int out_size, void* d_ws, size_t ws_size,
                              hipStream_t stream) {
    const float* cls   = (const float*)d_in[0];
    const float* codes = (const float*)d_in[1];
    const float* props = (const float*)d_in[2];
    float* out = (float*)d_out;

    const size_t mask_bytes   = (size_t)B_IMG * P_N * 64 * sizeof(unsigned int); // 8 MB
    const size_t packed_bytes = (size_t)B_IMG * P_N * sizeof(float4);            // 512 KB
    const bool use_mask = (ws_size >= mask_bytes + packed_bytes);

    unsigned int* mask = (unsigned int*)d_ws;
    float4* packed = (float4*)((char*)d_ws + mask_bytes);

    prep_sort_kernel<<<B_IMG, 1024, 0, stream>>>(cls, codes, props, out, packed,
                                                 use_mask ? 1 : 0);
    if (use_mask) {
        mask_kernel<<<B_IMG * (P_N / ROWS_PB), 512, 0, stream>>>(packed, mask);
        nms_kernel<true><<<B_IMG, 64, 0, stream>>>(out, mask);
    } else {
        nms_kernel<false><<<B_IMG, 64, 0, stream>>>(out, nullptr);
    }
}

// Round 2
// 152.120 us; speedup vs baseline: 1.3509x; 1.3509x over previous
//
#include <hip/hip_runtime.h>
#include <math.h>

#define B_IMG 16
#define P_N   2048

constexpr float SCORE_T = 0.05f;
constexpr float NMS_T   = 0.5f;
constexpr float XCLIP   = 4.135166556742356f; // log(1000/16)
constexpr float IMW     = 1333.0f;
constexpr float IMH     = 800.0f;

// monotone float->uint mapping (ascending float order, incl +inf)
__device__ __forceinline__ unsigned int fkey(float f) {
    unsigned int u = __float_as_uint(f);
    return (u & 0x80000000u) ? ~u : (u | 0x80000000u);
}

// ---------------------------------------------------------------------------
// Kernel A: score + decode + clip + stable sort; writes sorted rows to out
// ---------------------------------------------------------------------------
__global__ __launch_bounds__(1024) void prep_sort_kernel(
    const float* __restrict__ cls, const float* __restrict__ codes,
    const float* __restrict__ props, float* __restrict__ out,
    float4* __restrict__ packed, int write_packed)
{
#pragma clang fp contract(off)
    __shared__ float4 sbox[P_N];
    __shared__ float  ssc[P_N];
    __shared__ unsigned long long skey[P_N];

    const int img = blockIdx.x;
    const int tid = threadIdx.x;

    for (int p = tid; p < P_N; p += 1024) {
        float2 lg = reinterpret_cast<const float2*>(cls)[img * P_N + p];
        float score = 1.0f / (1.0f + expf(lg.x - lg.y));

        float4 pb = reinterpret_cast<const float4*>(props)[img * P_N + p];
        float4 c  = reinterpret_cast<const float4*>(codes)[(img * P_N + p) * 2 + 1];

        float w  = pb.z - pb.x + 1.0f;
        float h  = pb.w - pb.y + 1.0f;
        float cx = pb.x + 0.5f * w;
        float cy = pb.y + 0.5f * h;

        float dx = c.x / 10.0f;
        float dy = c.y / 10.0f;
        float dw = fminf(c.z / 5.0f, XCLIP);
        float dh = fminf(c.w / 5.0f, XCLIP);

        float pcx = dx * w + cx;
        float pcy = dy * h + cy;
        float pw  = expf(dw) * w;
        float ph  = expf(dh) * h;

        float x1 = pcx - 0.5f * pw;
        float y1 = pcy - 0.5f * ph;
        float x2 = (pcx + 0.5f * pw) - 1.0f;
        float y2 = (pcy + 0.5f * ph) - 1.0f;

        x1 = fminf(fmaxf(x1, 0.0f), IMW - 1.0f);
        y1 = fminf(fmaxf(y1, 0.0f), IMH - 1.0f);
        x2 = fminf(fmaxf(x2, 0.0f), IMW - 1.0f);
        y2 = fminf(fmaxf(y2, 0.0f), IMH - 1.0f);

        sbox[p] = make_float4(x1, y1, x2, y2);
        ssc[p]  = score;

        float key = (score > SCORE_T) ? -score : __int_as_float(0x7f800000); // +inf
        skey[p] = (((unsigned long long)fkey(key)) << 32) | (unsigned int)p;
    }
    __syncthreads();

    // bitonic sort ascending over 2048 u64 keys (stable argsort replica)
    for (int k = 2; k <= P_N; k <<= 1) {
        for (int j = k >> 1; j > 0; j >>= 1) {
            for (int t = tid; t < P_N; t += 1024) {
                int ixj = t ^ j;
                if (ixj > t) {
                    unsigned long long a = skey[t], b = skey[ixj];
                    bool up = ((t & k) == 0);
                    if ((a > b) == up) { skey[t] = b; skey[ixj] = a; }
                }
            }
            __syncthreads();
        }
    }

    // gather + write sorted rows
    for (int e = tid; e < P_N; e += 1024) {
        unsigned long long kv = skey[e];
        int idx = (int)(kv & 0xFFFFFFFFull);
        float4 b4 = sbox[idx];
        float  s  = ssc[idx];
        float* o = out + ((size_t)img * P_N + e) * 5;
        o[0] = b4.x; o[1] = b4.y; o[2] = b4.z; o[3] = b4.w; o[4] = s;
        if (write_packed) packed[img * P_N + e] = b4;
    }
}

// ---------------------------------------------------------------------------
// Kernel B: suppression bitmask rows (j > i && IoU > 0.5), ballot-packed
// ---------------------------------------------------------------------------
#define ROWS_PB 8
__global__ __launch_bounds__(512) void mask_kernel(
    const float4* __restrict__ packed, unsigned int* __restrict__ mask)
{
#pragma clang fp contract(off)
    __shared__ float4 sb[P_N];
    const int blocks_per_img = P_N / ROWS_PB; // 256
    const int img = blockIdx.x / blocks_per_img;
    const int rb  = blockIdx.x % blocks_per_img;
    const int tid = threadIdx.x;

    for (int j = tid; j < P_N; j += 512) sb[j] = packed[img * P_N + j];
    __syncthreads();

    const int wave = tid >> 6;
    const int lane = tid & 63;
    const int i = rb * ROWS_PB + wave;

    float4 bi = sb[i];
    float area_i = (bi.z - bi.x) * (bi.w - bi.y);

    unsigned int myword = 0;
    for (int c = 0; c < 32; ++c) {
        int j = c * 64 + lane;
        bool sup = false;
        if (j > i) {
            float4 bj = sb[j];
            float area_j = (bj.z - bj.x) * (bj.w - bj.y);
            float ltx = fmaxf(bi.x, bj.x);
            float lty = fmaxf(bi.y, bj.y);
            float rbx = fminf(bi.z, bj.z);
            float rby = fminf(bi.w, bj.w);
            float wx = fmaxf(rbx - ltx, 0.0f);
            float wy = fmaxf(rby - lty, 0.0f);
            float inter = wx * wy;
            float denom = ((area_i + area_j) - inter) + 1e-9f;
            sup = (inter / denom) > NMS_T;
        }
        unsigned long long m = __ballot(sup);
        if ((lane >> 1) == c)
            myword = (lane & 1) ? (unsigned int)(m >> 32) : (unsigned int)m;
    }
    mask[((size_t)img * P_N + i) * 64 + lane] = myword;
}

// ---------------------------------------------------------------------------
// Kernel C: sequential greedy cascade (1 wave per image), zero non-kept rows
//   Branchless step + 32-deep prefetch: chain = readlane + 2 SALU + v_and.
// ---------------------------------------------------------------------------
template <bool USE_MASK>
__global__ __launch_bounds__(64) void nms_kernel(
    float* __restrict__ out, const unsigned int* __restrict__ mask)
{
#pragma clang fp contract(off)
    __shared__ float4 sb[P_N];
    const int img  = blockIdx.x;
    const int lane = threadIdx.x;

    unsigned int keep = 0;
    for (int b = 0; b < 32; ++b) {
        int p = lane * 32 + b;
        const float* o = out + ((size_t)img * P_N + p) * 5;
        if constexpr (!USE_MASK) sb[p] = make_float4(o[0], o[1], o[2], o[3]);
        if (o[4] > SCORE_T) keep |= (1u << b);
    }
    if constexpr (!USE_MASK) __syncthreads();

    if constexpr (USE_MASK) {
        const unsigned int* mrow = mask + (size_t)img * P_N * 64 + lane;
        constexpr int PF = 32;               // 32-deep: ~640 cy in flight >= L3 latency
        static_assert(P_N % PF == 0, "");
        unsigned int buf[PF];
#pragma unroll
        for (int k = 0; k < PF; ++k) buf[k] = mrow[(size_t)k * 64];
        for (int base = 0; base < P_N; base += PF) {
#pragma unroll
            for (int k = 0; k < PF; ++k) {
                int i = base + k;
                unsigned int m = buf[k];
                int nxt = i + PF;
                // clamp address (value unused on last tile) - keeps loads in-bounds
                buf[k] = mrow[(size_t)(nxt < P_N ? nxt : i) * 64];
                unsigned int kw =
                    (unsigned int)__builtin_amdgcn_readlane((int)keep, i >> 5);
                unsigned int bc = 0u - ((kw >> (i & 31)) & 1u); // all-ones if kept
                keep &= ~(m & bc);                              // branchless
            }
        }
    } else {
        for (int i = 0; i < P_N; ++i) {
            unsigned int kw =
                (unsigned int)__builtin_amdgcn_readlane((int)keep, i >> 5);
            if ((kw >> (i & 31)) & 1u) {
                float4 bi = sb[i];
                float area_i = (bi.z - bi.x) * (bi.w - bi.y);
                unsigned int m = 0;
                for (int b = 0; b < 32; ++b) {
                    int j = lane * 32 + b;
                    if (j > i) {
                        float4 bj = sb[j];
                        float area_j = (bj.z - bj.x) * (bj.w - bj.y);
                        float ltx = fmaxf(bi.x, bj.x);
                        float lty = fmaxf(bi.y, bj.y);
                        float rbx = fminf(bi.z, bj.z);
                        float rby = fminf(bi.w, bj.w);
                        float wx = fmaxf(rbx - ltx, 0.0f);
                        float wy = fmaxf(rby - lty, 0.0f);
                        float inter = wx * wy;
                        float denom = ((area_i + area_j) - inter) + 1e-9f;
                        if ((inter / denom) > NMS_T) m |= (1u << b);
                    }
                }
                keep &= ~m;
            }
        }
    }

    // zero out non-kept rows
    for (int b = 0; b < 32; ++b) {
        if (!((keep >> b) & 1u)) {
            int p = lane * 32 + b;
            float* o = out + ((size_t)img * P_N + p) * 5;
            o[0] = 0.0f; o[1] = 0.0f; o[2] = 0.0f; o[3] = 0.0f; o[4] = 0.0f;
        }
    }
}

// ---------------------------------------------------------------------------
extern "C" void kernel_launch(void* const* d_in, const int* in_sizes, int n_in,
                              void* d_out, int out_size, void* d_ws, size_t ws_size,
                              hipStream_t stream) {
    const float* cls   = (const float*)d_in[0];
    const float* codes = (const float*)d_in[1];
    const float* props = (const float*)d_in[2];
    float* out = (float*)d_out;

    const size_t mask_bytes   = (size_t)B_IMG * P_N * 64 * sizeof(unsigned int); // 8 MB
    const size_t packed_bytes = (size_t)B_IMG * P_N * sizeof(float4);            // 512 KB
    const bool use_mask = (ws_size >= mask_bytes + packed_bytes);

    unsigned int* mask = (unsigned int*)d_ws;
    float4* packed = (float4*)((char*)d_ws + mask_bytes);

    prep_sort_kernel<<<B_IMG, 1024, 0, stream>>>(cls, codes, props, out, packed,
                                                 use_mask ? 1 : 0);
    if (use_mask) {
        mask_kernel<<<B_IMG * (P_N / ROWS_PB), 512, 0, stream>>>(packed, mask);
        nms_kernel<true><<<B_IMG, 64, 0, stream>>>(out, mask);
    } else {
        nms_kernel<false><<<B_IMG, 64, 0, stream>>>(out, nullptr);
    }
}

// Round 3
// 140.839 us; speedup vs baseline: 1.4591x; 1.0801x over previous
//
#include <hip/hip_runtime.h>
#include <math.h>

#define B_IMG 16
#define P_N   2048
#define NBLK  (P_N / 64)   // 32 blocks of 64 rows

constexpr float SCORE_T = 0.05f;
constexpr float NMS_T   = 0.5f;
constexpr float XCLIP   = 4.135166556742356f; // log(1000/16)
constexpr float IMW     = 1333.0f;
constexpr float IMH     = 800.0f;

// monotone float->uint mapping (ascending float order, incl +inf)
__device__ __forceinline__ unsigned int fkey(float f) {
    unsigned int u = __float_as_uint(f);
    return (u & 0x80000000u) ? ~u : (u | 0x80000000u);
}

// ---------------------------------------------------------------------------
// Kernel A: score + decode + clip + stable sort; writes sorted rows to out
// ---------------------------------------------------------------------------
__global__ __launch_bounds__(1024) void prep_sort_kernel(
    const float* __restrict__ cls, const float* __restrict__ codes,
    const float* __restrict__ props, float* __restrict__ out)
{
#pragma clang fp contract(off)
    __shared__ float4 sbox[P_N];
    __shared__ float  ssc[P_N];
    __shared__ unsigned long long skey[P_N];

    const int img = blockIdx.x;
    const int tid = threadIdx.x;

    for (int p = tid; p < P_N; p += 1024) {
        float2 lg = reinterpret_cast<const float2*>(cls)[img * P_N + p];
        float score = 1.0f / (1.0f + expf(lg.x - lg.y));

        float4 pb = reinterpret_cast<const float4*>(props)[img * P_N + p];
        float4 c  = reinterpret_cast<const float4*>(codes)[(img * P_N + p) * 2 + 1];

        float w  = pb.z - pb.x + 1.0f;
        float h  = pb.w - pb.y + 1.0f;
        float cx = pb.x + 0.5f * w;
        float cy = pb.y + 0.5f * h;

        float dx = c.x / 10.0f;
        float dy = c.y / 10.0f;
        float dw = fminf(c.z / 5.0f, XCLIP);
        float dh = fminf(c.w / 5.0f, XCLIP);

        float pcx = dx * w + cx;
        float pcy = dy * h + cy;
        float pw  = expf(dw) * w;
        float ph  = expf(dh) * h;

        float x1 = pcx - 0.5f * pw;
        float y1 = pcy - 0.5f * ph;
        float x2 = (pcx + 0.5f * pw) - 1.0f;
        float y2 = (pcy + 0.5f * ph) - 1.0f;

        x1 = fminf(fmaxf(x1, 0.0f), IMW - 1.0f);
        y1 = fminf(fmaxf(y1, 0.0f), IMH - 1.0f);
        x2 = fminf(fmaxf(x2, 0.0f), IMW - 1.0f);
        y2 = fminf(fmaxf(y2, 0.0f), IMH - 1.0f);

        sbox[p] = make_float4(x1, y1, x2, y2);
        ssc[p]  = score;

        float key = (score > SCORE_T) ? -score : __int_as_float(0x7f800000); // +inf
        skey[p] = (((unsigned long long)fkey(key)) << 32) | (unsigned int)p;
    }
    __syncthreads();

    // bitonic sort ascending over 2048 u64 keys (stable argsort replica)
    for (int k = 2; k <= P_N; k <<= 1) {
        for (int j = k >> 1; j > 0; j >>= 1) {
            for (int t = tid; t < P_N; t += 1024) {
                int ixj = t ^ j;
                if (ixj > t) {
                    unsigned long long a = skey[t], b = skey[ixj];
                    bool up = ((t & k) == 0);
                    if ((a > b) == up) { skey[t] = b; skey[ixj] = a; }
                }
            }
            __syncthreads();
        }
    }

    // gather + write sorted rows
    for (int e = tid; e < P_N; e += 1024) {
        unsigned long long kv = skey[e];
        int idx = (int)(kv & 0xFFFFFFFFull);
        float4 b4 = sbox[idx];
        float  s  = ssc[idx];
        float* o = out + ((size_t)img * P_N + e) * 5;
        o[0] = b4.x; o[1] = b4.y; o[2] = b4.z; o[3] = b4.w; o[4] = s;
    }
}

// ---------------------------------------------------------------------------
// Kernel B: transposed suppression bitmask + per-row 64-bit diagonal rows.
//   tmask[(img*P + i)*64 + lane] bit w  = sup(i, w*64+lane)   (j>i included)
//   diag[img*P + i] bit j               = sup(i, (i>>6)*64+j)
// ---------------------------------------------------------------------------
#define ROWS_PB 8
__global__ __launch_bounds__(512) void mask_kernel(
    const float* __restrict__ out, unsigned int* __restrict__ tmask,
    unsigned long long* __restrict__ diag)
{
#pragma clang fp contract(off)
    __shared__ float4 sb[P_N];
    const int blocks_per_img = P_N / ROWS_PB; // 256
    const int img = blockIdx.x / blocks_per_img;
    const int rb  = blockIdx.x % blocks_per_img;
    const int tid = threadIdx.x;

    for (int j = tid; j < P_N; j += 512) {
        const float* o = out + ((size_t)img * P_N + j) * 5;
        sb[j] = make_float4(o[0], o[1], o[2], o[3]);
    }
    __syncthreads();

    const int wave = tid >> 6;
    const int lane = tid & 63;
    const int i = rb * ROWS_PB + wave;

    float4 bi = sb[i];
    float area_i = (bi.z - bi.x) * (bi.w - bi.y);

    unsigned int tw = 0;
    for (int w = 0; w < NBLK; ++w) {
        int j = w * 64 + lane;
        float4 bj = sb[j];
        float area_j = (bj.z - bj.x) * (bj.w - bj.y);
        float ltx = fmaxf(bi.x, bj.x);
        float lty = fmaxf(bi.y, bj.y);
        float rbx = fminf(bi.z, bj.z);
        float rby = fminf(bi.w, bj.w);
        float wx = fmaxf(rbx - ltx, 0.0f);
        float wy = fmaxf(rby - lty, 0.0f);
        float inter = wx * wy;
        float denom = ((area_i + area_j) - inter) + 1e-9f;
        bool sup = (j > i) && ((inter / denom) > NMS_T);
        tw |= (sup ? 1u : 0u) << w;
    }
    tmask[((size_t)img * P_N + i) * 64 + lane] = tw;

    unsigned long long d = __ballot(((tw >> (i >> 6)) & 1u) != 0u);
    if (lane == 0) diag[(size_t)img * P_N + i] = d;
}

// ---------------------------------------------------------------------------
// Kernel C: blocked cascade, 1 wave/image. Serial work = #kept rows only.
// ---------------------------------------------------------------------------
__global__ __launch_bounds__(64) void nms_cascade(
    float* __restrict__ out, const unsigned int* __restrict__ tmask,
    const unsigned long long* __restrict__ diag)
{
    const int img  = blockIdx.x;
    const int lane = threadIdx.x;
    const unsigned int* tm = tmask + (size_t)img * P_N * 64 + lane;
    const unsigned long long* dg = diag + (size_t)img * P_N;

    unsigned int S = 0;      // bit b = row b*64+lane suppressed by earlier kept
    unsigned int keepv = 0;  // bit b = row b*64+lane kept

    unsigned int bufA[64], bufB[64];
    unsigned long long dA, dB;
    float scA, scB;

    // prefetch block 0 into A
#pragma unroll
    for (int r = 0; r < 64; ++r) bufA[r] = tm[(size_t)r * 64];
    dA = dg[lane];
    scA = out[((size_t)img * P_N + lane) * 5 + 4];

    auto body = [&](int b, unsigned int (&cur)[64], unsigned long long& dcur, float& sccur,
                    unsigned int (&nxt)[64], unsigned long long& dnxt, float& scnxt) {
        const int nb = (b + 1 < NBLK) ? b + 1 : b; // clamp: last iter reloads same
        const int nbase = nb * 64;
#pragma unroll
        for (int r = 0; r < 64; ++r) nxt[r] = tm[(size_t)(nbase + r) * 64];
        dnxt  = dg[nbase + lane];
        scnxt = out[((size_t)img * P_N + nbase + lane) * 5 + 4];

        unsigned long long validb = __ballot(sccur > SCORE_T);
        unsigned long long supb   = __ballot(((S >> b) & 1u) != 0u);
        unsigned long long alive  = validb & ~supb;
        unsigned long long kept   = 0;
        while (alive) {
            int i = __builtin_ctzll(alive);
            kept |= 1ull << i;
            unsigned int lo = (unsigned int)__builtin_amdgcn_readlane(
                (int)(unsigned int)(dcur & 0xffffffffull), i);
            unsigned int hi = (unsigned int)__builtin_amdgcn_readlane(
                (int)(unsigned int)(dcur >> 32), i);
            unsigned long long rm = (((unsigned long long)hi) << 32) | lo;
            alive &= ~(rm | (1ull << i));
        }
        keepv |= ((unsigned int)((kept >> lane) & 1ull)) << b;
#pragma unroll
        for (int r = 0; r < 64; ++r) {
            unsigned int bc = 0u - (unsigned int)((kept >> r) & 1ull);
            S |= cur[r] & bc;
        }
    };

    for (int b = 0; b < NBLK; b += 2) {
        body(b,     bufA, dA, scA, bufB, dB, scB);
        body(b + 1, bufB, dB, scB, bufA, dA, scA);
    }

    // zero out non-kept rows
    for (int b = 0; b < NBLK; ++b) {
        if (!((keepv >> b) & 1u)) {
            float* o = out + ((size_t)img * P_N + b * 64 + lane) * 5;
            o[0] = 0.0f; o[1] = 0.0f; o[2] = 0.0f; o[3] = 0.0f; o[4] = 0.0f;
        }
    }
}

// ---------------------------------------------------------------------------
// Fallback (small ws): on-the-fly serial cascade, 1 wave/image
// ---------------------------------------------------------------------------
__global__ __launch_bounds__(64) void nms_fallback(float* __restrict__ out)
{
#pragma clang fp contract(off)
    __shared__ float4 sb[P_N];
    const int img  = blockIdx.x;
    const int lane = threadIdx.x;

    unsigned int keep = 0;
    for (int b = 0; b < 32; ++b) {
        int p = lane * 32 + b;
        const float* o = out + ((size_t)img * P_N + p) * 5;
        sb[p] = make_float4(o[0], o[1], o[2], o[3]);
        if (o[4] > SCORE_T) keep |= (1u << b);
    }
    __syncthreads();

    for (int i = 0; i < P_N; ++i) {
        unsigned int kw =
            (unsigned int)__builtin_amdgcn_readlane((int)keep, i >> 5);
        if ((kw >> (i & 31)) & 1u) {
            float4 bi = sb[i];
            float area_i = (bi.z - bi.x) * (bi.w - bi.y);
            unsigned int m = 0;
            for (int b = 0; b < 32; ++b) {
                int j = lane * 32 + b;
                if (j > i) {
                    float4 bj = sb[j];
                    float area_j = (bj.z - bj.x) * (bj.w - bj.y);
                    float ltx = fmaxf(bi.x, bj.x);
                    float lty = fmaxf(bi.y, bj.y);
                    float rbx = fminf(bi.z, bj.z);
                    float rby = fminf(bi.w, bj.w);
                    float wx = fmaxf(rbx - ltx, 0.0f);
                    float wy = fmaxf(rby - lty, 0.0f);
                    float inter = wx * wy;
                    float denom = ((area_i + area_j) - inter) + 1e-9f;
                    if ((inter / denom) > NMS_T) m |= (1u << b);
                }
            }
            keep &= ~m;
        }
    }

    for (int b = 0; b < 32; ++b) {
        if (!((keep >> b) & 1u)) {
            int p = lane * 32 + b;
            float* o = out + ((size_t)img * P_N + p) * 5;
            o[0] = 0.0f; o[1] = 0.0f; o[2] = 0.0f; o[3] = 0.0f; o[4] = 0.0f;
        }
    }
}

// ---------------------------------------------------------------------------
extern "C" void kernel_launch(void* const* d_in, const int* in_sizes, int n_in,
                              void* d_out, int out_size, void* d_ws, size_t ws_size,
                              hipStream_t stream) {
    const float* cls   = (const float*)d_in[0];
    const float* codes = (const float*)d_in[1];
    const float* props = (const float*)d_in[2];
    float* out = (float*)d_out;

    const size_t tmask_bytes = (size_t)B_IMG * P_N * 64 * sizeof(unsigned int);      // 8 MB
    const size_t diag_bytes  = (size_t)B_IMG * P_N * sizeof(unsigned long long);     // 256 KB
    const bool use_mask = (ws_size >= tmask_bytes + diag_bytes);

    unsigned int* tmask = (unsigned int*)d_ws;
    unsigned long long* diag = (unsigned long long*)((char*)d_ws + tmask_bytes);

    prep_sort_kernel<<<B_IMG, 1024, 0, stream>>>(cls, codes, props, out);
    if (use_mask) {
        mask_kernel<<<B_IMG * (P_N / ROWS_PB), 512, 0, stream>>>(out, tmask, diag);
        nms_cascade<<<B_IMG, 64, 0, stream>>>(out, tmask, diag);
    } else {
        nms_fallback<<<B_IMG, 64, 0, stream>>>(out);
    }
}

// Round 4
// 139.164 us; speedup vs baseline: 1.4766x; 1.0120x over previous
//
#include <hip/hip_runtime.h>
#include <math.h>

#define B_IMG 16
#define P_N   2048
#define NBLK  (P_N / 64)   // 32 blocks of 64 rows

constexpr float SCORE_T = 0.05f;
constexpr float NMS_T   = 0.5f;
constexpr float XCLIP   = 4.135166556742356f; // log(1000/16)
constexpr float IMW     = 1333.0f;
constexpr float IMH     = 800.0f;

// monotone float->uint mapping (ascending float order, incl +inf)
__device__ __forceinline__ unsigned int fkey(float f) {
    unsigned int u = __float_as_uint(f);
    return (u & 0x80000000u) ? ~u : (u | 0x80000000u);
}

// ---------------------------------------------------------------------------
// Kernel A: score + decode + clip + stable sort; writes sorted rows to out
// ---------------------------------------------------------------------------
__global__ __launch_bounds__(1024) void prep_sort_kernel(
    const float* __restrict__ cls, const float* __restrict__ codes,
    const float* __restrict__ props, float* __restrict__ out)
{
#pragma clang fp contract(off)
    __shared__ float4 sbox[P_N];
    __shared__ float  ssc[P_N];
    __shared__ unsigned long long skey[P_N];

    const int img = blockIdx.x;
    const int tid = threadIdx.x;

    for (int p = tid; p < P_N; p += 1024) {
        float2 lg = reinterpret_cast<const float2*>(cls)[img * P_N + p];
        float score = 1.0f / (1.0f + expf(lg.x - lg.y));

        float4 pb = reinterpret_cast<const float4*>(props)[img * P_N + p];
        float4 c  = reinterpret_cast<const float4*>(codes)[(img * P_N + p) * 2 + 1];

        float w  = pb.z - pb.x + 1.0f;
        float h  = pb.w - pb.y + 1.0f;
        float cx = pb.x + 0.5f * w;
        float cy = pb.y + 0.5f * h;

        float dx = c.x / 10.0f;
        float dy = c.y / 10.0f;
        float dw = fminf(c.z / 5.0f, XCLIP);
        float dh = fminf(c.w / 5.0f, XCLIP);

        float pcx = dx * w + cx;
        float pcy = dy * h + cy;
        float pw  = expf(dw) * w;
        float ph  = expf(dh) * h;

        float x1 = pcx - 0.5f * pw;
        float y1 = pcy - 0.5f * ph;
        float x2 = (pcx + 0.5f * pw) - 1.0f;
        float y2 = (pcy + 0.5f * ph) - 1.0f;

        x1 = fminf(fmaxf(x1, 0.0f), IMW - 1.0f);
        y1 = fminf(fmaxf(y1, 0.0f), IMH - 1.0f);
        x2 = fminf(fmaxf(x2, 0.0f), IMW - 1.0f);
        y2 = fminf(fmaxf(y2, 0.0f), IMH - 1.0f);

        sbox[p] = make_float4(x1, y1, x2, y2);
        ssc[p]  = score;

        float key = (score > SCORE_T) ? -score : __int_as_float(0x7f800000); // +inf
        skey[p] = (((unsigned long long)fkey(key)) << 32) | (unsigned int)p;
    }
    __syncthreads();

    // bitonic sort ascending over 2048 u64 keys (stable argsort replica)
    for (int k = 2; k <= P_N; k <<= 1) {
        for (int j = k >> 1; j > 0; j >>= 1) {
            for (int t = tid; t < P_N; t += 1024) {
                int ixj = t ^ j;
                if (ixj > t) {
                    unsigned long long a = skey[t], b = skey[ixj];
                    bool up = ((t & k) == 0);
                    if ((a > b) == up) { skey[t] = b; skey[ixj] = a; }
                }
            }
            __syncthreads();
        }
    }

    // gather + write sorted rows
    for (int e = tid; e < P_N; e += 1024) {
        unsigned long long kv = skey[e];
        int idx = (int)(kv & 0xFFFFFFFFull);
        float4 b4 = sbox[idx];
        float  s  = ssc[idx];
        float* o = out + ((size_t)img * P_N + e) * 5;
        o[0] = b4.x; o[1] = b4.y; o[2] = b4.z; o[3] = b4.w; o[4] = s;
    }
}

// ---------------------------------------------------------------------------
// Kernel B: transposed suppression bitmask + per-row 64-bit diagonal rows.
//   tmask[(img*P + i)*64 + lane] bit w  = sup(i, w*64+lane)   (j>i only)
//   diag[img*P + i] bit j               = sup(i, (i>>6)*64+j)
//   Only w-blocks >= i's block computed (j>i requirement) -> ~2x less work.
// ---------------------------------------------------------------------------
#define ROWS_PB 8
__global__ __launch_bounds__(512) void mask_kernel(
    const float* __restrict__ out, unsigned int* __restrict__ tmask,
    unsigned long long* __restrict__ diag)
{
#pragma clang fp contract(off)
    __shared__ float4 sb[P_N];
    const int blocks_per_img = P_N / ROWS_PB; // 256
    const int img = blockIdx.x / blocks_per_img;
    const int rb  = blockIdx.x % blocks_per_img;
    const int tid = threadIdx.x;
    const int wstart = rb >> 3;   // i>>6 for all 8 rows of this block

    for (int j = wstart * 64 + tid; j < P_N; j += 512) {
        const float* o = out + ((size_t)img * P_N + j) * 5;
        sb[j] = make_float4(o[0], o[1], o[2], o[3]);
    }
    __syncthreads();

    const int wave = tid >> 6;
    const int lane = tid & 63;
    const int i = rb * ROWS_PB + wave;

    float4 bi = sb[i];
    float area_i = (bi.z - bi.x) * (bi.w - bi.y);

    unsigned int tw = 0;
    for (int w = wstart; w < NBLK; ++w) {
        int j = w * 64 + lane;
        float4 bj = sb[j];
        float area_j = (bj.z - bj.x) * (bj.w - bj.y);
        float ltx = fmaxf(bi.x, bj.x);
        float lty = fmaxf(bi.y, bj.y);
        float rbx = fminf(bi.z, bj.z);
        float rby = fminf(bi.w, bj.w);
        float wx = fmaxf(rbx - ltx, 0.0f);
        float wy = fmaxf(rby - lty, 0.0f);
        float inter = wx * wy;
        float denom = ((area_i + area_j) - inter) + 1e-9f;
        bool sup = (j > i) && ((inter / denom) > NMS_T);
        tw |= (sup ? 1u : 0u) << w;
    }
    tmask[((size_t)img * P_N + i) * 64 + lane] = tw;

    unsigned long long d = __ballot(((tw >> wstart) & 1u) != 0u);
    if (lane == 0) diag[(size_t)img * P_N + i] = d;
}

// ---------------------------------------------------------------------------
// Kernel C: blocked cascade, producer/consumer 2 waves per image.
//   wave 1: streams next mask block (16 KB) global -> LDS (global_load_lds)
//   wave 0: serial cascade on current block from LDS; sc/diag prefetch 1 ahead
// ---------------------------------------------------------------------------
__global__ __launch_bounds__(128) void nms_cascade(
    float* __restrict__ out, const unsigned int* __restrict__ tmask,
    const unsigned long long* __restrict__ diag)
{
    __shared__ unsigned int dbuf[2][64][64];   // 32 KB double buffer
    const int img  = blockIdx.x;
    const int tid  = threadIdx.x;
    const int wv   = tid >> 6;
    const int lane = tid & 63;

    const unsigned int* tmi = tmask + (size_t)img * P_N * 64;

    unsigned long long dgA = 0, dgB = 0;
    float scA = 0.0f, scB = 0.0f;

    if (wv == 1) {
        // producer prologue: stage block 0 into dbuf[0]
        for (int r = 0; r < 64; ++r) {
            __builtin_amdgcn_global_load_lds(
                (const __attribute__((address_space(1))) unsigned int*)
                    (tmi + (size_t)r * 64 + lane),
                (__attribute__((address_space(3))) unsigned int*)&dbuf[0][r][0],
                4, 0, 0);
        }
        asm volatile("s_waitcnt vmcnt(0)" ::: "memory");
    } else {
        dgA = diag[(size_t)img * P_N + lane];
        scA = out[((size_t)img * P_N + lane) * 5 + 4];
    }
    __syncthreads();

    unsigned int S = 0;      // bit b = row b*64+lane suppressed by earlier kept
    unsigned int keepv = 0;  // bit b = row b*64+lane kept

    for (int b = 0; b < NBLK; ++b) {
        if (wv == 1) {
            if (b + 1 < NBLK) {
                for (int r = 0; r < 64; ++r) {
                    __builtin_amdgcn_global_load_lds(
                        (const __attribute__((address_space(1))) unsigned int*)
                            (tmi + ((size_t)(b + 1) * 64 + r) * 64 + lane),
                        (__attribute__((address_space(3))) unsigned int*)
                            &dbuf[(b + 1) & 1][r][0],
                        4, 0, 0);
                }
                asm volatile("s_waitcnt vmcnt(0)" ::: "memory");
            }
        } else {
            // issue next block's sc/diag loads early (covered by this body)
            const int nb = (b + 1 < NBLK) ? b + 1 : b;
            dgB = diag[(size_t)img * P_N + nb * 64 + lane];
            scB = out[((size_t)img * P_N + nb * 64 + lane) * 5 + 4];

            // current mask block from LDS
            unsigned int cur[64];
#pragma unroll
            for (int r = 0; r < 64; ++r) cur[r] = dbuf[b & 1][r][lane];

            unsigned long long validb = __ballot(scA > SCORE_T);
            unsigned long long supb   = __ballot(((S >> b) & 1u) != 0u);
            unsigned long long alive  = validb & ~supb;
            unsigned long long kept   = 0;
            unsigned int dlo = (unsigned int)(dgA & 0xffffffffull);
            unsigned int dhi = (unsigned int)(dgA >> 32);
            while (alive) {
                int i = __builtin_ctzll(alive);
                kept |= 1ull << i;
                unsigned int lo = (unsigned int)__builtin_amdgcn_readlane((int)dlo, i);
                unsigned int hi = (unsigned int)__builtin_amdgcn_readlane((int)dhi, i);
                unsigned long long rm = (((unsigned long long)hi) << 32) | lo;
                alive &= ~(rm | (1ull << i));
            }
            keepv |= ((unsigned int)((kept >> lane) & 1ull)) << b;
#pragma unroll
            for (int r = 0; r < 64; ++r) {
                unsigned int bc = 0u - (unsigned int)((kept >> r) & 1ull);
                S |= cur[r] & bc;
            }
            dgA = dgB; scA = scB;
        }
        __syncthreads();
    }

    // zero out non-kept rows (consumer wave holds keepv)
    if (wv == 0) {
        for (int b = 0; b < NBLK; ++b) {
            if (!((keepv >> b) & 1u)) {
                float* o = out + ((size_t)img * P_N + b * 64 + lane) * 5;
                o[0] = 0.0f; o[1] = 0.0f; o[2] = 0.0f; o[3] = 0.0f; o[4] = 0.0f;
            }
        }
    }
}

// ---------------------------------------------------------------------------
// Fallback (small ws): on-the-fly serial cascade, 1 wave/image
// ---------------------------------------------------------------------------
__global__ __launch_bounds__(64) void nms_fallback(float* __restrict__ out)
{
#pragma clang fp contract(off)
    __shared__ float4 sb[P_N];
    const int img  = blockIdx.x;
    const int lane = threadIdx.x;

    unsigned int keep = 0;
    for (int b = 0; b < 32; ++b) {
        int p = lane * 32 + b;
        const float* o = out + ((size_t)img * P_N + p) * 5;
        sb[p] = make_float4(o[0], o[1], o[2], o[3]);
        if (o[4] > SCORE_T) keep |= (1u << b);
    }
    __syncthreads();

    for (int i = 0; i < P_N; ++i) {
        unsigned int kw =
            (unsigned int)__builtin_amdgcn_readlane((int)keep, i >> 5);
        if ((kw >> (i & 31)) & 1u) {
            float4 bi = sb[i];
            float area_i = (bi.z - bi.x) * (bi.w - bi.y);
            unsigned int m = 0;
            for (int b = 0; b < 32; ++b) {
                int j = lane * 32 + b;
                if (j > i) {
                    float4 bj = sb[j];
                    float area_j = (bj.z - bj.x) * (bj.w - bj.y);
                    float ltx = fmaxf(bi.x, bj.x);
                    float lty = fmaxf(bi.y, bj.y);
                    float rbx = fminf(bi.z, bj.z);
                    float rby = fminf(bi.w, bj.w);
                    float wx = fmaxf(rbx - ltx, 0.0f);
                    float wy = fmaxf(rby - lty, 0.0f);
                    float inter = wx * wy;
                    float denom = ((area_i + area_j) - inter) + 1e-9f;
                    if ((inter / denom) > NMS_T) m |= (1u << b);
                }
            }
            keep &= ~m;
        }
    }

    for (int b = 0; b < 32; ++b) {
        if (!((keep >> b) & 1u)) {
            int p = lane * 32 + b;
            float* o = out + ((size_t)img * P_N + p) * 5;
            o[0] = 0.0f; o[1] = 0.0f; o[2] = 0.0f; o[3] = 0.0f; o[4] = 0.0f;
        }
    }
}

// ---------------------------------------------------------------------------
extern "C" void kernel_launch(void* const* d_in, const int* in_sizes, int n_in,
                              void* d_out, int out_size, void* d_ws, size_t ws_size,
                              hipStream_t stream) {
    const float* cls   = (const float*)d_in[0];
    const float* codes = (const float*)d_in[1];
    const float* props = (const float*)d_in[2];
    float* out = (float*)d_out;

    const size_t tmask_bytes = (size_t)B_IMG * P_N * 64 * sizeof(unsigned int);   // 8 MB
    const size_t diag_bytes  = (size_t)B_IMG * P_N * sizeof(unsigned long long);  // 256 KB
    const bool use_mask = (ws_size >= tmask_bytes + diag_bytes);

    unsigned int* tmask = (unsigned int*)d_ws;
    unsigned long long* diag = (unsigned long long*)((char*)d_ws + tmask_bytes);

    prep_sort_kernel<<<B_IMG, 1024, 0, stream>>>(cls, codes, props, out);
    if (use_mask) {
        mask_kernel<<<B_IMG * (P_N / ROWS_PB), 512, 0, stream>>>(out, tmask, diag);
        nms_cascade<<<B_IMG, 128, 0, stream>>>(out, tmask, diag);
    } else {
        nms_fallback<<<B_IMG, 64, 0, stream>>>(out);
    }
}